// Round 17
// baseline (571.911 us; speedup 1.0000x reference)
//
#include <hip/hip_runtime.h>
#include <math.h>

#define NN 4096
#define DD 64
#define NA 8192
#define NR 8192
#define NC (NN + NA + NR)  // 20480
#define KS 6
#define KA 3
#define KR 10
#define EE (NN * (KS - 1))

#define CH 256                     // candidate rows per chunk
#define NCH0 (NN / CH)             // 16
#define NCH1 (NA / CH)             // 32
#define NCH2 (NR / CH)             // 32
#define NCHT (NCH0 + NCH1 + NCH2)  // 80
#define GROUPS (NN / 128)          // 32 groups of 128 nodes (32/wave)

typedef __attribute__((ext_vector_type(8))) short bf16x8;
typedef __attribute__((ext_vector_type(16))) float f32x16;
typedef unsigned long long u64;
#define MFMA32 __builtin_amdgcn_mfma_f32_32x32x16_bf16

// Selection keys are POSITIVE FINITE DOUBLES whose bit pattern is
// (fp32 dist bits << 32) | candidate idx. For positive finite IEEE doubles,
// numeric order == bit-pattern order, so v_min_f64/v_max_f64 (1 inst each)
// compute results bit-identical to u64 compare-select chains.
// EXACT keys + 3-level split are MANDATORY: R7/R11 (quantized keys, even at
// a 2.4e-7 grid) both failed absmax 0.111 — boundary gap < 2.4e-7.
// Sentinel = DBL_MAX bits (NOT ~0ull: NaN pattern corrupts fmin/fmax nets).
#define SENTBITS 0x7FEFFFFFFFFFFFFFull

__device__ __forceinline__ ushort f2bf(float f) {  // RN-even fp32->bf16
    unsigned u = __float_as_uint(f);
    u += 0x7fffu + ((u >> 16) & 1u);
    return (ushort)(u >> 16);
}
__device__ __forceinline__ float bf2f(ushort b) {
    return __uint_as_float(((unsigned)b) << 16);
}
__device__ __forceinline__ double packdi(float d, int i) {
    // dist >= 0 -> sign bit 0; exponent field from dist[30:20] < 0x7FF
    const u64 bits = (((u64)__float_as_uint(d)) << 32) | (unsigned)i;
    return __longlong_as_double((long long)bits);
}
__device__ __forceinline__ float updist(u64 p) {
    return __uint_as_float((unsigned)(p >> 32));
}
__device__ __forceinline__ int upidx(u64 p) { return (int)(p & 0xffffffffu); }

__device__ __forceinline__ void casd(double& a, double& b) {
    const double mn = fmin(a, b);  // v_min_f64
    const double mx = fmax(a, b);  // v_max_f64
    a = mn;
    b = mx;
}

// Batcher odd-even mergesort on N contiguous double keys (fully unrolled).
template <int N>
__device__ __forceinline__ void sortN(double* S) {
#pragma unroll
    for (int p = 1; p < N; p <<= 1) {
#pragma unroll
        for (int k = p; k > 0; k >>= 1) {
#pragma unroll
            for (int j = k % p; j + k < N; j += 2 * k) {
#pragma unroll
                for (int i = 0; i < k; ++i) {
                    if (i + j + k < N &&
                        (i + j) / (2 * p) == (i + j + k) / (2 * p))
                        casd(S[i + j], S[i + j + k]);
                }
            }
        }
    }
}

// R[k] = k-th smallest of union of sorted A[NA_] and B[NB_], k < K. Exact.
template <int K, int NA_, int NB_>
__device__ __forceinline__ void mergeTop(const double* A, const double* B,
                                         double* R) {
#pragma unroll
    for (int k = 0; k < K; ++k) {
        double m = __longlong_as_double((long long)SENTBITS);
        if (k < NA_) m = A[k];
        if (k < NB_) m = fmin(m, B[k]);
#pragma unroll
        for (int i = 0; i < k; ++i) {
            const int j = k - 1 - i;
            if (i < NA_ && j < NB_) m = fmin(m, fmax(A[i], B[j]));
        }
        R[k] = m;
    }
}

// Merge this tile's 16 exact keys into sorted bd[K] (branch-free, exact).
template <int K>
__device__ __forceinline__ void tileSelect(double (&bd)[K], double (&S)[16]) {
    double nb[K];
    if constexpr (K == 10) {
        sortN<16>(S);
        mergeTop<10, 10, 16>(bd, S, nb);
    } else if constexpr (K == 6) {
        sortN<8>(S);
        sortN<8>(S + 8);
        double t[6];
        mergeTop<6, 8, 8>(S, S + 8, t);
        mergeTop<6, 6, 6>(bd, t, nb);
    } else {
        sortN<4>(S);
        sortN<4>(S + 4);
        sortN<4>(S + 8);
        sortN<4>(S + 12);
        double t0[3], t1[3], t2[3];
        mergeTop<3, 4, 4>(S, S + 4, t0);
        mergeTop<3, 4, 4>(S + 8, S + 12, t1);
        mergeTop<3, 3, 3>(t0, t1, t2);
        mergeTop<3, 3, 3>(bd, t2, nb);
    }
#pragma unroll
    for (int k = 0; k < K; ++k) bd[k] = nb[k];
}

// ---- split x into 3 bf16 levels + fp32 row norms (one wave per row) ----
__global__ __launch_bounds__(256) void split_kernel(
    const float* __restrict__ x, int nrows, ushort* __restrict__ h,
    ushort* __restrict__ m, ushort* __restrict__ l, float* __restrict__ nrm) {
    const int idx = blockIdx.x * 256 + threadIdx.x;
    const int row = idx >> 6, lane = idx & 63;
    if (row >= nrows) return;
    const float xv = x[idx];  // row*64+lane == idx (DD=64)
    const ushort hb = f2bf(xv);
    const float r1 = xv - bf2f(hb);
    const ushort mb = f2bf(r1);
    const float r2 = r1 - bf2f(mb);
    const ushort lb = f2bf(r2);
    h[idx] = hb;
    m[idx] = mb;
    l[idx] = lb;
    float sq = xv * xv;
#pragma unroll
    for (int off = 32; off > 0; off >>= 1) sq += __shfl_xor(sq, off, 64);
    if (lane == 0) nrm[row] = sq;
}

// One 32x32 tile: load A fragments, 24 MFMAs (R10 order: hl,lh,mm,hm,mh,hh),
// pack 16 exact keys, merge into the GIVEN bd state.
template <int K>
__device__ __forceinline__ void tileBody(
    const ushort* __restrict__ ch, const ushort* __restrict__ cm,
    const ushort* __restrict__ cl, const float* __restrict__ cnormp,
    const bf16x8 (&bh)[4], const bf16x8 (&bm)[4], const bf16x8 (&bl)[4],
    float vn, int c0, int rowA, int r0, int kq, double (&bd)[K]) {
    const size_t ab = (size_t)(c0 + rowA) * DD + kq;
    bf16x8 ah[4], am[4], al[4];
#pragma unroll
    for (int m = 0; m < 4; ++m) {
        ah[m] = *(const bf16x8*)(ch + ab + 16 * m);
        am[m] = *(const bf16x8*)(cm + ab + 16 * m);
        al[m] = *(const bf16x8*)(cl + ab + 16 * m);
    }
    f32x16 acc = {0.f, 0.f, 0.f, 0.f, 0.f, 0.f, 0.f, 0.f,
                  0.f, 0.f, 0.f, 0.f, 0.f, 0.f, 0.f, 0.f};
#pragma unroll
    for (int m = 0; m < 4; ++m) {  // small products first, hh last
        acc = MFMA32(ah[m], bl[m], acc, 0, 0, 0);
        acc = MFMA32(al[m], bh[m], acc, 0, 0, 0);
        acc = MFMA32(am[m], bm[m], acc, 0, 0, 0);
        acc = MFMA32(ah[m], bm[m], acc, 0, 0, 0);
        acc = MFMA32(am[m], bh[m], acc, 0, 0, 0);
        acc = MFMA32(ah[m], bh[m], acc, 0, 0, 0);
    }
    double S[16];
#pragma unroll
    for (int b = 0; b < 4; ++b) {
        const float4 cn = *(const float4*)(cnormp + c0 + r0 + 8 * b);
        const float cna[4] = {cn.x, cn.y, cn.z, cn.w};
#pragma unroll
        for (int a = 0; a < 4; ++a) {
            const float dist = fmaxf(vn + cna[a] - 2.f * acc[b * 4 + a], 0.f);
            S[b * 4 + a] = packdi(dist, c0 + r0 + 8 * b + a);
        }
    }
    tileSelect<K>(bd, S);
}

// ---- 32x32 MFMA distance sweep + sort/ladder top-K over one 256-cand chunk.
// A = 32 candidate rows, B = 32 node cols; lane owns ONE node (col=lane&31)
// and 16 candidate rows: row = (reg&3) + 8*(reg>>2) + 4*(lane>>5).
// R17: TWO independent top-K states (bd even tiles / bd2 odd tiles), exact
// mergeTop at chunk end. Breaks the loop-carried ~230-cyc serial f64 select
// chain (R16's unroll was neutral because both tiles fed ONE bd). Selection
// result identical: top-K(union) = merge(top-K(even), top-K(odd)).
template <int K>
__device__ __forceinline__ void sweep_impl(
    const ushort* __restrict__ ch, const ushort* __restrict__ cm,
    const ushort* __restrict__ cl, const float* __restrict__ cnormp,
    const ushort* __restrict__ vh, const ushort* __restrict__ vm,
    const ushort* __restrict__ vl, const float* __restrict__ vnormp,
    u64* __restrict__ pp, int nchp, int up, int g) {
    const int tid = threadIdx.x, wave = tid >> 6, lane = tid & 63;
    const int n0 = g * 128 + wave * 32;
    const int node = n0 + (lane & 31);
    const int kq = (lane >> 5) * 8;  // k sub-offset within each 16-k chunk

    // B fragments: this node's vector, 4 k-chunks x 3 levels (chunk-resident)
    const size_t vb = (size_t)node * DD + kq;
    bf16x8 bh[4], bm[4], bl[4];
#pragma unroll
    for (int m = 0; m < 4; ++m) {
        bh[m] = *(const bf16x8*)(vh + vb + 16 * m);
        bm[m] = *(const bf16x8*)(vm + vb + 16 * m);
        bl[m] = *(const bf16x8*)(vl + vb + 16 * m);
    }
    const float vn = vnormp[node];

    double bd[K], bd2[K];
#pragma unroll
    for (int k = 0; k < K; ++k) {
        bd[k] = __longlong_as_double((long long)SENTBITS);
        bd2[k] = __longlong_as_double((long long)SENTBITS);
    }

    const int cbase = up * CH;
    const int rowA = lane & 31;
    const int r0 = (lane >> 5) * 4;  // C-row base component

#pragma unroll
    for (int t = 0; t < CH / 32; t += 2) {
        // even tile -> bd, odd tile -> bd2: independent select chains
        tileBody<K>(ch, cm, cl, cnormp, bh, bm, bl, vn, cbase + t * 32, rowA,
                    r0, kq, bd);
        tileBody<K>(ch, cm, cl, cnormp, bh, bm, bl, vn, cbase + (t + 1) * 32,
                    rowA, r0, kq, bd2);
    }
    // combine the two partial lists (exact), then the 2 lanes per node
    double bdc[K], pb[K], od[K];
    mergeTop<K, K, K>(bd, bd2, bdc);
#pragma unroll
    for (int k = 0; k < K; ++k) pb[k] = __shfl_xor(bdc[k], 32, 64);
    mergeTop<K, K, K>(bdc, pb, od);
    if (lane < 32) {
        const int n = n0 + lane;
        const size_t base = ((size_t)n * nchp + up) * K;
#pragma unroll
        for (int k = 0; k < K; ++k)
            pp[base + k] = (u64)__double_as_longlong(od[k]);
    }
}

// grid: GROUPS * NCHT uniform blocks; chunk id selects phase. No LDS.
__global__ __launch_bounds__(256) void sweep_kernel(
    const ushort* __restrict__ ch, const ushort* __restrict__ cm,
    const ushort* __restrict__ cl, const float* __restrict__ cnorm,
    const ushort* __restrict__ vh, const ushort* __restrict__ vm,
    const ushort* __restrict__ vl, const float* __restrict__ vnorm,
    u64* __restrict__ pp) {
    const int g = blockIdx.x / NCHT;
    const int u = blockIdx.x % NCHT;
    const size_t o1 = (size_t)NN * DD, o2 = (size_t)(NN + NA) * DD;
    const size_t p1 = (size_t)NN * NCH0 * KS;
    const size_t p2 = p1 + (size_t)NN * NCH1 * KA;
    if (u < NCH0) {
        sweep_impl<KS>(ch, cm, cl, cnorm, vh, vm, vl, vnorm, pp, NCH0, u, g);
    } else if (u < NCH0 + NCH1) {
        sweep_impl<KA>(ch + o1, cm + o1, cl + o1, cnorm + NN, vh, vm, vl,
                       vnorm, pp + p1, NCH1, u - NCH0, g);
    } else {
        sweep_impl<KR>(ch + o2, cm + o2, cl + o2, cnorm + NN + NA, vh, vm, vl,
                       vnorm, pp + p2, NCH2, u - NCH0 - NCH1, g);
    }
}

// ---- merge NCH chunk-lists per node (LDS two-pointer tree, u64) ----
template <int K, int NCH>
__device__ __forceinline__ void mergeN(const u64* __restrict__ pp, int n,
                                       u64* __restrict__ w, int lane) {
    __syncthreads();
    for (int j = lane; j < NCH * K; j += 64)
        w[j] = pp[(size_t)n * NCH * K + j];
    __syncthreads();
#pragma unroll
    for (int off = NCH / 2; off >= 1; off >>= 1) {
        if (lane < off) {
            const int a0 = lane * K, b0 = (lane + off) * K;
            u64 md[K];
            int p = 0, q = 0;
#pragma unroll
            for (int k = 0; k < K; ++k) {  // p+q==k<K: in-bounds
                const u64 av = w[a0 + p];
                const u64 bv = w[b0 + q];
                const bool ta = av < bv;
                md[k] = ta ? av : bv;
                if (ta) ++p; else ++q;
            }
#pragma unroll
            for (int k = 0; k < K; ++k) w[a0 + k] = md[k];
        }
        __syncthreads();
    }
}

__global__ __launch_bounds__(256) void finalize_kernel(
    const float* __restrict__ v, const float* __restrict__ attr,
    const float* __restrict__ rep, const u64* __restrict__ pp,
    float* __restrict__ move_self, float* __restrict__ mv_rn,
    int* __restrict__ ia_out, int* __restrict__ tgt_out) {
    __shared__ u64 sp[4][NCH2 * KR];  // 4 x 320 x 8B = 10 KB
    const int wave = threadIdx.x >> 6, lane = threadIdx.x & 63;
    const int n = blockIdx.x * 4 + wave;
    const float vv = v[n * DD + lane];
    const size_t p1 = (size_t)NN * NCH0 * KS;
    const size_t p2 = p1 + (size_t)NN * NCH1 * KA;

    // phase 0: edges (skip rank 0)
    mergeN<KS, NCH0>(pp, n, sp[wave], lane);
    if (lane < KS - 1) tgt_out[n * (KS - 1) + lane] = upidx(sp[wave][1 + lane]);

    // phase 1: attracts
    mergeN<KA, NCH1>(pp + p1, n, sp[wave], lane);
    float mva = 0.f;
    if (lane < KA) ia_out[n * KA + lane] = upidx(sp[wave][lane]);
#pragma unroll
    for (int k = 0; k < KA; ++k) {
        const float dx = updist(sp[wave][k]);
        const int ik = upidx(sp[wave][k]);
        const float t = dx * 10.f;  // _rayleigh(dx,0.1,0.1)
        const float eo = dx * expf(-0.5f * t * t);
        mva = fmaf(eo, attr[(size_t)ik * DD + lane] - vv, mva);
    }

    // phase 2: repels
    mergeN<KR, NCH2>(pp + p2, n, sp[wave], lane);
    float mr = 0.f, mrn = 0.f;
#pragma unroll
    for (int k = 0; k < KR; ++k) {
        const float dx = updist(sp[wave][k]);
        const int ik = upidx(sp[wave][k]);
        const float er = 0.1f * expf(-0.1f * dx * dx);       // _negexp(.,0.1,0.1)
        const float ern = 0.006f * expf(-0.006f * dx * dx);  // _negexp(.,0.006,0.006)
        const float diff = rep[(size_t)ik * DD + lane] - vv;
        mr = fmaf(er, diff, mr);
        mrn = fmaf(ern, diff, mrn);
    }
    move_self[n * DD + lane] = mva - mr;
    mv_rn[n * DD + lane] = mrn;
}

// one wave per edge; 4 edges per block
__global__ __launch_bounds__(256) void edge_kernel(
    const float* __restrict__ v, const float* __restrict__ attr,
    const int* __restrict__ ia, const int* __restrict__ tgt,
    float* __restrict__ nb_attr, float* __restrict__ indeg) {
    const int lane = threadIdx.x & 63;
    const int w = threadIdx.x >> 6;
    const int e = blockIdx.x * 4 + w;
    if (e >= EE) return;
    const int s = e / (KS - 1);
    const int t = tgt[e];
    const float vj = v[t * DD + lane];
    float acc = 0.f;
#pragma unroll
    for (int k = 0; k < KA; ++k) {
        const int g = ia[s * KA + k];
        const float diff = attr[(size_t)g * DD + lane] - vj;
        float sq = diff * diff;
#pragma unroll
        for (int off = 32; off > 0; off >>= 1) sq += __shfl_xor(sq, off, 64);
        const float r = sq / 0.006f;  // _rayleigh(dx,0.006,0.006)
        const float eon = sq * expf(-0.5f * r * r);
        acc = fmaf(eon, diff, acc);
    }
    atomicAdd(&nb_attr[t * DD + lane], acc);
    if (lane == 0) atomicAdd(&indeg[t], 1.0f);
}

__global__ __launch_bounds__(256) void update_kernel(
    const float* __restrict__ v, const float* __restrict__ ms,
    const float* __restrict__ nba, const float* __restrict__ mrn,
    const float* __restrict__ indeg, float* __restrict__ vout) {
    const int i = blockIdx.x * 256 + threadIdx.x;
    if (i >= NN * DD) return;
    const int n = i >> 6;
    vout[i] = v[i] + ms[i] + nba[i] - indeg[n] * mrn[i];
}

extern "C" void kernel_launch(void* const* d_in, const int* in_sizes, int n_in,
                              void* d_out, int out_size, void* d_ws,
                              size_t ws_size, hipStream_t stream) {
    const float* data = (const float*)d_in[0];
    const float* attr = (const float*)d_in[1];
    const float* rep = (const float*)d_in[2];
    // d_in[3] = epochs (fixed to 3 per setup_inputs)

    char* p = (char*)d_ws;
    auto alloc = [&](size_t bytes) {
        bytes = (bytes + 255) & ~(size_t)255;
        char* r = p;
        p += bytes;
        return (void*)r;
    };
    float* va = (float*)alloc(NN * DD * 4);
    float* vb = (float*)alloc(NN * DD * 4);
    float* ms = (float*)alloc(NN * DD * 4);
    float* mrn = (float*)alloc(NN * DD * 4);
    float* nba = (float*)alloc(NN * DD * 4 + NN * 4);  // nba + indeg contiguous
    float* indeg = nba + NN * DD;
    float* cnorm = (float*)alloc(NC * 4);
    float* vnorm = (float*)alloc(NN * 4);
    ushort* chv = (ushort*)alloc((size_t)NC * DD * 2);
    ushort* cmv = (ushort*)alloc((size_t)NC * DD * 2);
    ushort* clv = (ushort*)alloc((size_t)NC * DD * 2);
    ushort* vhb = (ushort*)alloc((size_t)NN * DD * 2);
    ushort* vmb = (ushort*)alloc((size_t)NN * DD * 2);
    ushort* vlb = (ushort*)alloc((size_t)NN * DD * 2);
    const size_t NPART =
        (size_t)NN * (NCH0 * KS + NCH1 * KA + NCH2 * KR);  // 4096*512
    u64* pp = (u64*)alloc(NPART * 8);
    int* ia = (int*)alloc(NN * KA * 4);
    int* tgt = (int*)alloc(NN * (KS - 1) * 4);

    // split all candidates (data|attr|rep) into bf16 h/m/l + norms, once
    split_kernel<<<NN * DD / 256, 256, 0, stream>>>(data, NN, chv, cmv, clv,
                                                    cnorm);
    split_kernel<<<NA * DD / 256, 256, 0, stream>>>(
        attr, NA, chv + (size_t)NN * DD, cmv + (size_t)NN * DD,
        clv + (size_t)NN * DD, cnorm + NN);
    split_kernel<<<NR * DD / 256, 256, 0, stream>>>(
        rep, NR, chv + (size_t)(NN + NA) * DD, cmv + (size_t)(NN + NA) * DD,
        clv + (size_t)(NN + NA) * DD, cnorm + NN + NA);

    const float* vcur = data;
    float* outs[3] = {va, vb, (float*)d_out};
    for (int ep = 0; ep < 3; ++ep) {
        const ushort *evh, *evm, *evl;
        const float* evn;
        if (ep == 0) {  // v == data: reuse candidate splits (first NN rows)
            evh = chv; evm = cmv; evl = clv; evn = cnorm;
        } else {
            split_kernel<<<NN * DD / 256, 256, 0, stream>>>(vcur, NN, vhb, vmb,
                                                            vlb, vnorm);
            evh = vhb; evm = vmb; evl = vlb; evn = vnorm;
        }
        sweep_kernel<<<GROUPS * NCHT, 256, 0, stream>>>(chv, cmv, clv, cnorm,
                                                        evh, evm, evl, evn, pp);
        finalize_kernel<<<NN / 4, 256, 0, stream>>>(vcur, attr, rep, pp, ms,
                                                    mrn, ia, tgt);
        hipMemsetAsync(nba, 0, (NN * DD + NN) * sizeof(float), stream);
        edge_kernel<<<(EE + 3) / 4, 256, 0, stream>>>(vcur, attr, ia, tgt, nba,
                                                      indeg);
        update_kernel<<<NN * DD / 256, 256, 0, stream>>>(vcur, ms, nba, mrn,
                                                         indeg, outs[ep]);
        vcur = outs[ep];
    }
}

// Round 18
// 551.583 us; speedup vs baseline: 1.0369x; 1.0369x over previous
//
#include <hip/hip_runtime.h>
#include <math.h>

#define NN 4096
#define DD 64
#define NA 8192
#define NR 8192
#define NC (NN + NA + NR)  // 20480
#define KS 6
#define KA 3
#define KR 10
#define EE (NN * (KS - 1))

#define CH 256                     // candidate rows per chunk
#define NCH0 (NN / CH)             // 16
#define NCH1 (NA / CH)             // 32
#define NCH2 (NR / CH)             // 32
#define NCHT (NCH0 + NCH1 + NCH2)  // 80
#define GROUPS (NN / 128)          // 32 groups of 128 nodes (32/wave)

typedef __attribute__((ext_vector_type(8))) short bf16x8;
typedef __attribute__((ext_vector_type(16))) float f32x16;
typedef unsigned long long u64;
#define MFMA32 __builtin_amdgcn_mfma_f32_32x32x16_bf16

// Selection keys are POSITIVE FINITE DOUBLES whose bit pattern is
// (fp32 dist bits << 32) | candidate idx. For positive finite IEEE doubles,
// numeric order == bit-pattern order, so v_min_f64/v_max_f64 (1 inst each)
// compute results bit-identical to u64 compare-select chains.
// EXACT keys + 3-level split are MANDATORY: R7/R11 (quantized keys, even at
// a 2.4e-7 grid) both failed absmax 0.111 — boundary gap < 2.4e-7.
// Sentinel = DBL_MAX bits (NOT ~0ull: NaN pattern corrupts fmin/fmax nets).
#define SENTBITS 0x7FEFFFFFFFFFFFFFull

__device__ __forceinline__ ushort f2bf(float f) {  // RN-even fp32->bf16
    unsigned u = __float_as_uint(f);
    u += 0x7fffu + ((u >> 16) & 1u);
    return (ushort)(u >> 16);
}
__device__ __forceinline__ float bf2f(ushort b) {
    return __uint_as_float(((unsigned)b) << 16);
}
__device__ __forceinline__ double packdi(float d, int i) {
    // dist >= 0 -> sign bit 0; exponent field from dist[30:20] < 0x7FF
    const u64 bits = (((u64)__float_as_uint(d)) << 32) | (unsigned)i;
    return __longlong_as_double((long long)bits);
}
__device__ __forceinline__ float updist(u64 p) {
    return __uint_as_float((unsigned)(p >> 32));
}
__device__ __forceinline__ int upidx(u64 p) { return (int)(p & 0xffffffffu); }

__device__ __forceinline__ void casd(double& a, double& b) {
    const double mn = fmin(a, b);  // v_min_f64
    const double mx = fmax(a, b);  // v_max_f64
    a = mn;
    b = mx;
}

// Batcher odd-even mergesort on N contiguous double keys (fully unrolled).
template <int N>
__device__ __forceinline__ void sortN(double* S) {
#pragma unroll
    for (int p = 1; p < N; p <<= 1) {
#pragma unroll
        for (int k = p; k > 0; k >>= 1) {
#pragma unroll
            for (int j = k % p; j + k < N; j += 2 * k) {
#pragma unroll
                for (int i = 0; i < k; ++i) {
                    if (i + j + k < N &&
                        (i + j) / (2 * p) == (i + j + k) / (2 * p))
                        casd(S[i + j], S[i + j + k]);
                }
            }
        }
    }
}

// R[k] = k-th smallest of union of sorted A[NA_] and B[NB_], k < K. Exact.
template <int K, int NA_, int NB_>
__device__ __forceinline__ void mergeTop(const double* A, const double* B,
                                         double* R) {
#pragma unroll
    for (int k = 0; k < K; ++k) {
        double m = __longlong_as_double((long long)SENTBITS);
        if (k < NA_) m = A[k];
        if (k < NB_) m = fmin(m, B[k]);
#pragma unroll
        for (int i = 0; i < k; ++i) {
            const int j = k - 1 - i;
            if (i < NA_ && j < NB_) m = fmin(m, fmax(A[i], B[j]));
        }
        R[k] = m;
    }
}

// Merge this tile's 16 exact keys into sorted bd[K] (branch-free, exact).
template <int K>
__device__ __forceinline__ void tileSelect(double (&bd)[K], double (&S)[16]) {
    double nb[K];
    if constexpr (K == 10) {
        sortN<16>(S);
        mergeTop<10, 10, 16>(bd, S, nb);
    } else if constexpr (K == 6) {
        sortN<8>(S);
        sortN<8>(S + 8);
        double t[6];
        mergeTop<6, 8, 8>(S, S + 8, t);
        mergeTop<6, 6, 6>(bd, t, nb);
    } else {
        sortN<4>(S);
        sortN<4>(S + 4);
        sortN<4>(S + 8);
        sortN<4>(S + 12);
        double t0[3], t1[3], t2[3];
        mergeTop<3, 4, 4>(S, S + 4, t0);
        mergeTop<3, 4, 4>(S + 8, S + 12, t1);
        mergeTop<3, 3, 3>(t0, t1, t2);
        mergeTop<3, 3, 3>(bd, t2, nb);
    }
#pragma unroll
    for (int k = 0; k < K; ++k) bd[k] = nb[k];
}

// ---- split x into 3 bf16 levels + fp32 row norms (one wave per row) ----
__global__ __launch_bounds__(256) void split_kernel(
    const float* __restrict__ x, int nrows, ushort* __restrict__ h,
    ushort* __restrict__ m, ushort* __restrict__ l, float* __restrict__ nrm) {
    const int idx = blockIdx.x * 256 + threadIdx.x;
    const int row = idx >> 6, lane = idx & 63;
    if (row >= nrows) return;
    const float xv = x[idx];  // row*64+lane == idx (DD=64)
    const ushort hb = f2bf(xv);
    const float r1 = xv - bf2f(hb);
    const ushort mb = f2bf(r1);
    const float r2 = r1 - bf2f(mb);
    const ushort lb = f2bf(r2);
    h[idx] = hb;
    m[idx] = mb;
    l[idx] = lb;
    float sq = xv * xv;
#pragma unroll
    for (int off = 32; off > 0; off >>= 1) sq += __shfl_xor(sq, off, 64);
    if (lane == 0) nrm[row] = sq;
}

// ---- 32x32 MFMA distance sweep + sort/ladder top-K over one 256-cand chunk.
// A = 32 candidate rows, B = 32 node cols; lane owns ONE node (col=lane&31)
// and 16 candidate rows: row = (reg&3) + 8*(reg>>2) + 4*(lane>>5).
// MFMA product order bit-identical to R10: hl, lh, mm, hm, mh, hh.
// R18 (I-cache theory): t-loop FORCED ROLLED (#pragma unroll 1) — the
// unrolled body was ~25-40KB x 3 phase variants interleaved per CU, thrashing
// the shared I-cache (explains R15/R16/R17's invariant 170us wall with all
// issue ports idle). Rolled body ~3KB loops hot. Per-tile op order unchanged
// -> bit-identical selection.
template <int K>
__device__ __forceinline__ void sweep_impl(
    const ushort* __restrict__ ch, const ushort* __restrict__ cm,
    const ushort* __restrict__ cl, const float* __restrict__ cnormp,
    const ushort* __restrict__ vh, const ushort* __restrict__ vm,
    const ushort* __restrict__ vl, const float* __restrict__ vnormp,
    u64* __restrict__ pp, int nchp, int up, int g) {
    const int tid = threadIdx.x, wave = tid >> 6, lane = tid & 63;
    const int n0 = g * 128 + wave * 32;
    const int node = n0 + (lane & 31);
    const int kq = (lane >> 5) * 8;  // k sub-offset within each 16-k chunk

    // B fragments: this node's vector, 4 k-chunks x 3 levels (chunk-resident)
    const size_t vb = (size_t)node * DD + kq;
    bf16x8 bh[4], bm[4], bl[4];
#pragma unroll
    for (int m = 0; m < 4; ++m) {
        bh[m] = *(const bf16x8*)(vh + vb + 16 * m);
        bm[m] = *(const bf16x8*)(vm + vb + 16 * m);
        bl[m] = *(const bf16x8*)(vl + vb + 16 * m);
    }
    const float vn = vnormp[node];

    double bd[K];
#pragma unroll
    for (int k = 0; k < K; ++k)
        bd[k] = __longlong_as_double((long long)SENTBITS);

    const int cbase = up * CH;
    const int rowA = lane & 31;
    const int r0 = (lane >> 5) * 4;  // C-row base component

#pragma unroll 1
    for (int t = 0; t < CH / 32; ++t) {
        const int c0 = cbase + t * 32;
        const size_t ab = (size_t)(c0 + rowA) * DD + kq;
        bf16x8 ah[4], am[4], al[4];
#pragma unroll
        for (int m = 0; m < 4; ++m) {
            ah[m] = *(const bf16x8*)(ch + ab + 16 * m);
            am[m] = *(const bf16x8*)(cm + ab + 16 * m);
            al[m] = *(const bf16x8*)(cl + ab + 16 * m);
        }
        f32x16 acc = {0.f, 0.f, 0.f, 0.f, 0.f, 0.f, 0.f, 0.f,
                      0.f, 0.f, 0.f, 0.f, 0.f, 0.f, 0.f, 0.f};
#pragma unroll
        for (int m = 0; m < 4; ++m) {  // small products first, hh last
            acc = MFMA32(ah[m], bl[m], acc, 0, 0, 0);
            acc = MFMA32(al[m], bh[m], acc, 0, 0, 0);
            acc = MFMA32(am[m], bm[m], acc, 0, 0, 0);
            acc = MFMA32(ah[m], bm[m], acc, 0, 0, 0);
            acc = MFMA32(am[m], bh[m], acc, 0, 0, 0);
            acc = MFMA32(ah[m], bh[m], acc, 0, 0, 0);
        }
        double S[16];
#pragma unroll
        for (int b = 0; b < 4; ++b) {
            const float4 cn = *(const float4*)(cnormp + c0 + r0 + 8 * b);
            const float cna[4] = {cn.x, cn.y, cn.z, cn.w};
#pragma unroll
            for (int a = 0; a < 4; ++a) {
                const float dist =
                    fmaxf(vn + cna[a] - 2.f * acc[b * 4 + a], 0.f);
                S[b * 4 + a] = packdi(dist, c0 + r0 + 8 * b + a);
            }
        }
        tileSelect<K>(bd, S);
    }
    // merge the 2 lanes holding the same node (lane, lane+32) via shuffle
    double pb[K], od[K];
#pragma unroll
    for (int k = 0; k < K; ++k) pb[k] = __shfl_xor(bd[k], 32, 64);
    mergeTop<K, K, K>(bd, pb, od);
    if (lane < 32) {
        const int n = n0 + lane;
        const size_t base = ((size_t)n * nchp + up) * K;
#pragma unroll
        for (int k = 0; k < K; ++k)
            pp[base + k] = (u64)__double_as_longlong(od[k]);
    }
}

// R18: CHUNK-MAJOR grid — c = blockIdx.x / GROUPS selects the chunk (and
// hence the phase code path), g = blockIdx.x % GROUPS the node group.
// Co-resident blocks now run the SAME phase code (I-cache share) and read
// the SAME candidate tiles (L1/L2 share). Pure renaming: same work -> same
// pp slots.
__global__ __launch_bounds__(256) void sweep_kernel(
    const ushort* __restrict__ ch, const ushort* __restrict__ cm,
    const ushort* __restrict__ cl, const float* __restrict__ cnorm,
    const ushort* __restrict__ vh, const ushort* __restrict__ vm,
    const ushort* __restrict__ vl, const float* __restrict__ vnorm,
    u64* __restrict__ pp) {
    const int c = blockIdx.x / GROUPS;
    const int g = blockIdx.x % GROUPS;
    const size_t o1 = (size_t)NN * DD, o2 = (size_t)(NN + NA) * DD;
    const size_t p1 = (size_t)NN * NCH0 * KS;
    const size_t p2 = p1 + (size_t)NN * NCH1 * KA;
    if (c < NCH0) {
        sweep_impl<KS>(ch, cm, cl, cnorm, vh, vm, vl, vnorm, pp, NCH0, c, g);
    } else if (c < NCH0 + NCH1) {
        sweep_impl<KA>(ch + o1, cm + o1, cl + o1, cnorm + NN, vh, vm, vl,
                       vnorm, pp + p1, NCH1, c - NCH0, g);
    } else {
        sweep_impl<KR>(ch + o2, cm + o2, cl + o2, cnorm + NN + NA, vh, vm, vl,
                       vnorm, pp + p2, NCH2, c - NCH0 - NCH1, g);
    }
}

// ---- merge NCH chunk-lists per node (LDS two-pointer tree, u64) ----
template <int K, int NCH>
__device__ __forceinline__ void mergeN(const u64* __restrict__ pp, int n,
                                       u64* __restrict__ w, int lane) {
    __syncthreads();
    for (int j = lane; j < NCH * K; j += 64)
        w[j] = pp[(size_t)n * NCH * K + j];
    __syncthreads();
#pragma unroll
    for (int off = NCH / 2; off >= 1; off >>= 1) {
        if (lane < off) {
            const int a0 = lane * K, b0 = (lane + off) * K;
            u64 md[K];
            int p = 0, q = 0;
#pragma unroll
            for (int k = 0; k < K; ++k) {  // p+q==k<K: in-bounds
                const u64 av = w[a0 + p];
                const u64 bv = w[b0 + q];
                const bool ta = av < bv;
                md[k] = ta ? av : bv;
                if (ta) ++p; else ++q;
            }
#pragma unroll
            for (int k = 0; k < K; ++k) w[a0 + k] = md[k];
        }
        __syncthreads();
    }
}

__global__ __launch_bounds__(256) void finalize_kernel(
    const float* __restrict__ v, const float* __restrict__ attr,
    const float* __restrict__ rep, const u64* __restrict__ pp,
    float* __restrict__ move_self, float* __restrict__ mv_rn,
    int* __restrict__ ia_out, int* __restrict__ tgt_out) {
    __shared__ u64 sp[4][NCH2 * KR];  // 4 x 320 x 8B = 10 KB
    const int wave = threadIdx.x >> 6, lane = threadIdx.x & 63;
    const int n = blockIdx.x * 4 + wave;
    const float vv = v[n * DD + lane];
    const size_t p1 = (size_t)NN * NCH0 * KS;
    const size_t p2 = p1 + (size_t)NN * NCH1 * KA;

    // phase 0: edges (skip rank 0)
    mergeN<KS, NCH0>(pp, n, sp[wave], lane);
    if (lane < KS - 1) tgt_out[n * (KS - 1) + lane] = upidx(sp[wave][1 + lane]);

    // phase 1: attracts
    mergeN<KA, NCH1>(pp + p1, n, sp[wave], lane);
    float mva = 0.f;
    if (lane < KA) ia_out[n * KA + lane] = upidx(sp[wave][lane]);
#pragma unroll
    for (int k = 0; k < KA; ++k) {
        const float dx = updist(sp[wave][k]);
        const int ik = upidx(sp[wave][k]);
        const float t = dx * 10.f;  // _rayleigh(dx,0.1,0.1)
        const float eo = dx * expf(-0.5f * t * t);
        mva = fmaf(eo, attr[(size_t)ik * DD + lane] - vv, mva);
    }

    // phase 2: repels
    mergeN<KR, NCH2>(pp + p2, n, sp[wave], lane);
    float mr = 0.f, mrn = 0.f;
#pragma unroll
    for (int k = 0; k < KR; ++k) {
        const float dx = updist(sp[wave][k]);
        const int ik = upidx(sp[wave][k]);
        const float er = 0.1f * expf(-0.1f * dx * dx);       // _negexp(.,0.1,0.1)
        const float ern = 0.006f * expf(-0.006f * dx * dx);  // _negexp(.,0.006,0.006)
        const float diff = rep[(size_t)ik * DD + lane] - vv;
        mr = fmaf(er, diff, mr);
        mrn = fmaf(ern, diff, mrn);
    }
    move_self[n * DD + lane] = mva - mr;
    mv_rn[n * DD + lane] = mrn;
}

// one wave per edge; 4 edges per block
__global__ __launch_bounds__(256) void edge_kernel(
    const float* __restrict__ v, const float* __restrict__ attr,
    const int* __restrict__ ia, const int* __restrict__ tgt,
    float* __restrict__ nb_attr, float* __restrict__ indeg) {
    const int lane = threadIdx.x & 63;
    const int w = threadIdx.x >> 6;
    const int e = blockIdx.x * 4 + w;
    if (e >= EE) return;
    const int s = e / (KS - 1);
    const int t = tgt[e];
    const float vj = v[t * DD + lane];
    float acc = 0.f;
#pragma unroll
    for (int k = 0; k < KA; ++k) {
        const int g = ia[s * KA + k];
        const float diff = attr[(size_t)g * DD + lane] - vj;
        float sq = diff * diff;
#pragma unroll
        for (int off = 32; off > 0; off >>= 1) sq += __shfl_xor(sq, off, 64);
        const float r = sq / 0.006f;  // _rayleigh(dx,0.006,0.006)
        const float eon = sq * expf(-0.5f * r * r);
        acc = fmaf(eon, diff, acc);
    }
    atomicAdd(&nb_attr[t * DD + lane], acc);
    if (lane == 0) atomicAdd(&indeg[t], 1.0f);
}

__global__ __launch_bounds__(256) void update_kernel(
    const float* __restrict__ v, const float* __restrict__ ms,
    const float* __restrict__ nba, const float* __restrict__ mrn,
    const float* __restrict__ indeg, float* __restrict__ vout) {
    const int i = blockIdx.x * 256 + threadIdx.x;
    if (i >= NN * DD) return;
    const int n = i >> 6;
    vout[i] = v[i] + ms[i] + nba[i] - indeg[n] * mrn[i];
}

extern "C" void kernel_launch(void* const* d_in, const int* in_sizes, int n_in,
                              void* d_out, int out_size, void* d_ws,
                              size_t ws_size, hipStream_t stream) {
    const float* data = (const float*)d_in[0];
    const float* attr = (const float*)d_in[1];
    const float* rep = (const float*)d_in[2];
    // d_in[3] = epochs (fixed to 3 per setup_inputs)

    char* p = (char*)d_ws;
    auto alloc = [&](size_t bytes) {
        bytes = (bytes + 255) & ~(size_t)255;
        char* r = p;
        p += bytes;
        return (void*)r;
    };
    float* va = (float*)alloc(NN * DD * 4);
    float* vb = (float*)alloc(NN * DD * 4);
    float* ms = (float*)alloc(NN * DD * 4);
    float* mrn = (float*)alloc(NN * DD * 4);
    float* nba = (float*)alloc(NN * DD * 4 + NN * 4);  // nba + indeg contiguous
    float* indeg = nba + NN * DD;
    float* cnorm = (float*)alloc(NC * 4);
    float* vnorm = (float*)alloc(NN * 4);
    ushort* chv = (ushort*)alloc((size_t)NC * DD * 2);
    ushort* cmv = (ushort*)alloc((size_t)NC * DD * 2);
    ushort* clv = (ushort*)alloc((size_t)NC * DD * 2);
    ushort* vhb = (ushort*)alloc((size_t)NN * DD * 2);
    ushort* vmb = (ushort*)alloc((size_t)NN * DD * 2);
    ushort* vlb = (ushort*)alloc((size_t)NN * DD * 2);
    const size_t NPART =
        (size_t)NN * (NCH0 * KS + NCH1 * KA + NCH2 * KR);  // 4096*512
    u64* pp = (u64*)alloc(NPART * 8);
    int* ia = (int*)alloc(NN * KA * 4);
    int* tgt = (int*)alloc(NN * (KS - 1) * 4);

    // split all candidates (data|attr|rep) into bf16 h/m/l + norms, once
    split_kernel<<<NN * DD / 256, 256, 0, stream>>>(data, NN, chv, cmv, clv,
                                                    cnorm);
    split_kernel<<<NA * DD / 256, 256, 0, stream>>>(
        attr, NA, chv + (size_t)NN * DD, cmv + (size_t)NN * DD,
        clv + (size_t)NN * DD, cnorm + NN);
    split_kernel<<<NR * DD / 256, 256, 0, stream>>>(
        rep, NR, chv + (size_t)(NN + NA) * DD, cmv + (size_t)(NN + NA) * DD,
        clv + (size_t)(NN + NA) * DD, cnorm + NN + NA);

    const float* vcur = data;
    float* outs[3] = {va, vb, (float*)d_out};
    for (int ep = 0; ep < 3; ++ep) {
        const ushort *evh, *evm, *evl;
        const float* evn;
        if (ep == 0) {  // v == data: reuse candidate splits (first NN rows)
            evh = chv; evm = cmv; evl = clv; evn = cnorm;
        } else {
            split_kernel<<<NN * DD / 256, 256, 0, stream>>>(vcur, NN, vhb, vmb,
                                                            vlb, vnorm);
            evh = vhb; evm = vmb; evl = vlb; evn = vnorm;
        }
        sweep_kernel<<<GROUPS * NCHT, 256, 0, stream>>>(chv, cmv, clv, cnorm,
                                                        evh, evm, evl, evn, pp);
        finalize_kernel<<<NN / 4, 256, 0, stream>>>(vcur, attr, rep, pp, ms,
                                                    mrn, ia, tgt);
        hipMemsetAsync(nba, 0, (NN * DD + NN) * sizeof(float), stream);
        edge_kernel<<<(EE + 3) / 4, 256, 0, stream>>>(vcur, attr, ia, tgt, nba,
                                                      indeg);
        update_kernel<<<NN * DD / 256, 256, 0, stream>>>(vcur, ms, nba, mrn,
                                                         indeg, outs[ep]);
        vcur = outs[ep];
    }
}